// Round 10
// baseline (428.353 us; speedup 1.0000x reference)
//
#include <hip/hip_runtime.h>
#include <cstdint>

#define BB 2048
#define TT 200
#define DD 128
#define H1 128
#define H2 64
#define MASK_PAD -4294967295.0f

typedef __attribute__((ext_vector_type(8))) short short8;
typedef __attribute__((ext_vector_type(4))) float floatx4;

// ws layout (float offsets)
#define WS_WQAC   0         // fp32 [128][128]  Wqac[d][h] = W0a+W0c
#define WS_WKT    16384     // fp32 [128][128]  WkT[h][d]  = (W0b-W0c)^T
#define WS_WDT    32768     // fp32 [128][128]  WdT[h][d]  = W0d^T
#define WS_W1TB   49152     // bf16 [64][128]   W1^T      (4096 float slots)
#define WS_A0T    53248     // fp32 [128][200]  a0^T      (25600)
#define WS_A1T    78848     // fp32 [64][200]   a1^T      (12800)
#define WS_LOGITS 91648     // fp32 [2048][200] raw logits (409600)
#define WS_QAS    501248    // fp32 [2048][128] qA        (262144)
#define WS_WBG    763392    // bf16 [2048][128][128] folded W_b (16777216 slots)

static __device__ __forceinline__ unsigned short f2bf(float x) {
  union { float f; unsigned int u; } v; v.f = x;
  unsigned int r = v.u + 0x7FFF + ((v.u >> 16) & 1);  // RNE
  return (unsigned short)(r >> 16);
}

// ---------------------------------------------------------------------------
// Fold: weight reshapes/transposes (one-time, tiny)
// ---------------------------------------------------------------------------
__global__ __launch_bounds__(256) void din_fold(
    const float* __restrict__ W0, const float* __restrict__ W1,
    const float* __restrict__ a0, const float* __restrict__ a1,
    float* __restrict__ ws) {
  int i = blockIdx.x * blockDim.x + threadIdx.x;
  if (i < 16384) {
    int d = i >> 7, h = i & 127;
    ws[WS_WQAC + i] = W0[d * 128 + h] + W0[(256 + d) * 128 + h];
    ws[WS_WKT + (h * 128 + d)] = W0[(128 + d) * 128 + h] - W0[(256 + d) * 128 + h];
    ws[WS_WDT + (h * 128 + d)] = W0[(384 + d) * 128 + h];
  } else if (i < 24576) {
    int j = i - 16384; int g = j >> 7, h = j & 127;
    ((unsigned short*)(ws + WS_W1TB))[j] = f2bf(W1[h * 64 + g]);
  } else if (i < 50176) {
    int j = i - 24576; int h = j / 200, t = j % 200;
    ws[WS_A0T + j] = a0[t * H1 + h];
  } else if (i < 62976) {
    int j = i - 50176; int g = j / 200, t = j % 200;
    ws[WS_A1T + j] = a1[t * H2 + g];
  }
}

// ---------------------------------------------------------------------------
// Wbuild: Wb_g[b][h][d] = bf16(WkT[h][d] + q[b][d]*WdT[h][d])  (64 MB, BW)
// ---------------------------------------------------------------------------
__global__ __launch_bounds__(256) void din_wbuild(
    const float* __restrict__ query, const float* __restrict__ ws,
    unsigned short* __restrict__ wbg) {
  int idx = blockIdx.x * 256 + threadIdx.x;   // 2048*2048
  int b = idx >> 11;
  int rem = idx & 2047;
  int h = rem >> 4;
  int d0 = (rem & 15) * 8;
  const float* wk = ws + WS_WKT + h * 128 + d0;
  const float* wd = ws + WS_WDT + h * 128 + d0;
  const float* qp = query + (size_t)b * DD + d0;
  short8 o;
  #pragma unroll
  for (int e = 0; e < 8; ++e) o[e] = (short)f2bf(wk[e] + qp[e] * wd[e]);
  *(short8*)(wbg + (size_t)b * 16384 + h * 128 + d0) = o;
}

// ---------------------------------------------------------------------------
// QA: qas_g[b][h] = b0[h] + sum_d q[b][d] * Wqac[d][h]
// ---------------------------------------------------------------------------
__global__ __launch_bounds__(128) void din_qa(
    const float* __restrict__ query, const float* __restrict__ b0,
    const float* __restrict__ ws, float* __restrict__ qas_g) {
  const int b = blockIdx.x;
  const int h = threadIdx.x;
  __shared__ float qsh[DD];
  qsh[h] = query[(size_t)b * DD + h];
  __syncthreads();
  float acc = b0[h];
  const float* wq = ws + WS_WQAC + h;
  #pragma unroll 8
  for (int d = 0; d < DD; ++d) acc += qsh[d] * wq[d * 128];
  qas_g[(size_t)b * H1 + h] = acc;
}

// ---------------------------------------------------------------------------
// Logits: ZERO barriers. One block per b, 4 fully independent waves.
// Wave w owns tiles mt = w, w+4, ... Per tile:
//   prefetched key frags -> GEMM1 (B from Wb_g via L2, C-init = qA)
//   -> PReLU(a0T float4) -> private LDS transpose -> GEMM2 (B = W1T, L1-hot)
//   -> PReLU(a1T) -> 16-lane shfl reduce -> raw logits to ws.
// ---------------------------------------------------------------------------
__global__ __launch_bounds__(256, 2) void din_logits(
    const float* __restrict__ key, const float* __restrict__ ws,
    const unsigned short* __restrict__ wbg, const float* __restrict__ qas_g,
    const float* __restrict__ b1, const float* __restrict__ Wout,
    const float* __restrict__ bout, float* __restrict__ lgout_all) {
  const int b = blockIdx.x;
  const int tid = threadIdx.x;
  const int w = tid >> 6;
  const int l = tid & 63;
  const int lr = l & 15;
  const int kgrp = l >> 4;

  __shared__ unsigned short A2[4][16 * 128];   // 16 KB, wave-private quarters

  const unsigned short* wb = wbg + (size_t)b * 16384;
  const unsigned short* w1 = (const unsigned short*)(ws + WS_W1TB);
  const float* a0T = ws + WS_A0T;
  const float* a1T = ws + WS_A1T;
  float* lgout = lgout_all + (size_t)b * TT;
  char* a2b = (char*)A2[w];

  // per-lane constants
  float qv[8];
  #pragma unroll
  for (int nt = 0; nt < 8; ++nt) qv[nt] = qas_g[(size_t)b * H1 + nt * 16 + lr];
  float b1v[4], wov[4];
  #pragma unroll
  for (int nt = 0; nt < 4; ++nt) {
    int g = nt * 16 + lr;
    b1v[nt] = b1[g]; wov[nt] = Wout[g];
  }
  const float bout0 = bout[0];

  // prologue: prefetch first tile's key rows
  float4 fa[8];
  {
    int trow = w * 16 + lr; if (trow > 199) trow = 199;
    const float* ar = key + ((size_t)b * TT + trow) * DD + kgrp * 8;
    #pragma unroll
    for (int ks = 0; ks < 4; ++ks) {
      fa[2 * ks]     = *(const float4*)(ar + ks * 32);
      fa[2 * ks + 1] = *(const float4*)(ar + ks * 32 + 4);
    }
  }

  #pragma unroll 1
  for (int mt = w; mt < 13; mt += 4) {
    // cvt prefetched key -> af
    short8 af[4];
    #pragma unroll
    for (int ks = 0; ks < 4; ++ks) {
      float4 f0 = fa[2 * ks], f1 = fa[2 * ks + 1];
      short8 t;
      t[0] = (short)f2bf(f0.x); t[1] = (short)f2bf(f0.y);
      t[2] = (short)f2bf(f0.z); t[3] = (short)f2bf(f0.w);
      t[4] = (short)f2bf(f1.x); t[5] = (short)f2bf(f1.y);
      t[6] = (short)f2bf(f1.z); t[7] = (short)f2bf(f1.w);
      af[ks] = t;
    }
    // prefetch next tile (clamped; harmless dup reads on last iter)
    {
      int trow = (mt + 4) * 16 + lr; if (trow > 199) trow = 199;
      const float* ar = key + ((size_t)b * TT + trow) * DD + kgrp * 8;
      #pragma unroll
      for (int ks = 0; ks < 4; ++ks) {
        fa[2 * ks]     = *(const float4*)(ar + ks * 32);
        fa[2 * ks + 1] = *(const float4*)(ar + ks * 32 + 4);
      }
    }

    // GEMM1: full width, C-init = qA (broadcast over rows)
    floatx4 acc1[8];
    #pragma unroll
    for (int nt = 0; nt < 8; ++nt) {
      acc1[nt][0] = qv[nt]; acc1[nt][1] = qv[nt];
      acc1[nt][2] = qv[nt]; acc1[nt][3] = qv[nt];
    }
    #pragma unroll
    for (int ks = 0; ks < 4; ++ks) {
      #pragma unroll
      for (int nt = 0; nt < 8; ++nt) {
        short8 bf = *(const short8*)(wb + (nt * 16 + lr) * 128 + ks * 32 + kgrp * 8);
        acc1[nt] = __builtin_amdgcn_mfma_f32_16x16x32_bf16(af[ks], bf, acc1[nt], 0, 0, 0);
      }
    }

    // epilogue 1: PReLU(a0), write H0 to wave-private LDS (swizzled)
    const int tbase = mt * 16 + kgrp * 4;
    const int tb = tbase > 196 ? 196 : tbase;
    #pragma unroll
    for (int nt = 0; nt < 8; ++nt) {
      int h = nt * 16 + lr;
      float4 a0q = *(const float4*)(a0T + h * 200 + tb);
      #pragma unroll
      for (int r = 0; r < 4; ++r) {
        int t_loc = kgrp * 4 + r;
        float v = acc1[nt][r];
        float a = ((const float*)&a0q)[r];
        v = v > 0.0f ? v : a * v;
        *(unsigned short*)(a2b + t_loc * 256 + ((h * 2) ^ ((t_loc & 7) << 4))) = f2bf(v);
      }
    }

    // GEMM2: A from private LDS, B = W1T (L1-hot, same addrs every tile)
    short8 a2f[4];
    #pragma unroll
    for (int ks = 0; ks < 4; ++ks) {
      a2f[ks] = *(const short8*)(a2b + lr * 256 +
                                 ((ks * 64 + kgrp * 16) ^ ((lr & 7) << 4)));
    }
    floatx4 acc2[4];
    #pragma unroll
    for (int nt = 0; nt < 4; ++nt) acc2[nt] = (floatx4)(0.0f);
    #pragma unroll
    for (int ks = 0; ks < 4; ++ks) {
      #pragma unroll
      for (int nt = 0; nt < 4; ++nt) {
        short8 bf = *(const short8*)(w1 + (nt * 16 + lr) * 128 + ks * 32 + kgrp * 8);
        acc2[nt] = __builtin_amdgcn_mfma_f32_16x16x32_bf16(a2f[ks], bf, acc2[nt], 0, 0, 0);
      }
    }

    // epilogue 2: +b1, PReLU(a1), *Wout, 16-lane reduce, write raw logits
    float p[4] = {0.f, 0.f, 0.f, 0.f};
    #pragma unroll
    for (int nt = 0; nt < 4; ++nt) {
      int g = nt * 16 + lr;
      float4 a1q = *(const float4*)(a1T + g * 200 + tb);
      #pragma unroll
      for (int r = 0; r < 4; ++r) {
        float x = acc2[nt][r] + b1v[nt];
        float a = ((const float*)&a1q)[r];
        x = x > 0.0f ? x : a * x;
        p[r] += x * wov[nt];
      }
    }
    #pragma unroll
    for (int m = 1; m < 16; m <<= 1) {
      #pragma unroll
      for (int r = 0; r < 4; ++r) p[r] += __shfl_xor(p[r], m);
    }
    if (lr == 0) {
      #pragma unroll
      for (int r = 0; r < 4; ++r) {
        int tg = tbase + r;
        if (tg < TT) lgout[tg] = bout0 + p[r];
      }
    }
  }
}

// ---------------------------------------------------------------------------
// PV (+mask+softmax): out[b][d] = softmax(masked logits) . val[b]
// ---------------------------------------------------------------------------
__global__ __launch_bounds__(256) void din_pv(
    const float* __restrict__ val, const int* __restrict__ mask,
    const float* __restrict__ logits, float* __restrict__ out) {
  const int b = blockIdx.x;
  const int tid = threadIdx.x;
  const int w = tid >> 6;
  const int l = tid & 63;
  __shared__ float eL[TT];
  __shared__ float red4[8];
  __shared__ float red[8 * DD];

  float lv = -INFINITY;
  if (tid < TT) {
    float lg = logits[(size_t)b * TT + tid];
    int mk = mask[(size_t)b * TT + tid];
    lv = (mk == 0) ? MASK_PAD : lg;
  }
  {
    float m = lv;
    #pragma unroll
    for (int off = 32; off >= 1; off >>= 1) m = fmaxf(m, __shfl_xor(m, off));
    if (l == 0) red4[w] = m;
  }
  __syncthreads();
  float mx = fmaxf(fmaxf(red4[0], red4[1]), fmaxf(red4[2], red4[3]));
  float e = (tid < TT) ? __expf(lv - mx) : 0.0f;
  {
    float s = e;
    #pragma unroll
    for (int off = 32; off >= 1; off >>= 1) s += __shfl_xor(s, off);
    if (l == 0) red4[4 + w] = s;
  }
  __syncthreads();
  float inv = 1.0f / (red4[4] + red4[5] + red4[6] + red4[7]);
  if (tid < TT) eL[tid] = e * inv;
  __syncthreads();

  const int group = tid >> 5;
  const int d4 = (tid & 31) * 4;
  const float* vb = val + (size_t)b * TT * DD;
  float4 acc4 = make_float4(0.f, 0.f, 0.f, 0.f);
  #pragma unroll 5
  for (int t = group * 25; t < group * 25 + 25; ++t) {
    float4 v = *(const float4*)(vb + (size_t)t * DD + d4);
    float wt = eL[t];
    acc4.x += wt * v.x; acc4.y += wt * v.y;
    acc4.z += wt * v.z; acc4.w += wt * v.w;
  }
  *(float4*)&red[group * DD + d4] = acc4;
  __syncthreads();
  if (tid < DD) {
    float s = 0.0f;
    #pragma unroll
    for (int g = 0; g < 8; ++g) s += red[g * DD + tid];
    out[(size_t)b * DD + tid] = s;
  }
}

extern "C" void kernel_launch(void* const* d_in, const int* in_sizes, int n_in,
                              void* d_out, int out_size, void* d_ws, size_t ws_size,
                              hipStream_t stream) {
  const float* query = (const float*)d_in[0];
  const float* key   = (const float*)d_in[1];
  const float* val   = (const float*)d_in[2];
  const int*   mask  = (const int*)d_in[3];
  const float* W0    = (const float*)d_in[4];
  const float* b0    = (const float*)d_in[5];
  const float* a0    = (const float*)d_in[6];
  const float* W1    = (const float*)d_in[7];
  const float* b1    = (const float*)d_in[8];
  const float* a1    = (const float*)d_in[9];
  const float* Wout  = (const float*)d_in[10];
  const float* bout  = (const float*)d_in[11];
  float* out = (float*)d_out;
  float* ws  = (float*)d_ws;
  unsigned short* wbg = (unsigned short*)(ws + WS_WBG);
  float* qas_g  = ws + WS_QAS;
  float* logits = ws + WS_LOGITS;

  hipLaunchKernelGGL(din_fold, dim3(246), dim3(256), 0, stream, W0, W1, a0, a1, ws);
  hipLaunchKernelGGL(din_wbuild, dim3(16384), dim3(256), 0, stream, query, ws, wbg);
  hipLaunchKernelGGL(din_qa, dim3(BB), dim3(128), 0, stream, query, b0, ws, qas_g);
  hipLaunchKernelGGL(din_logits, dim3(BB), dim3(256), 0, stream,
                     key, ws, wbg, qas_g, b1, Wout, bout, logits);
  hipLaunchKernelGGL(din_pv, dim3(BB), dim3(256), 0, stream, val, mask, logits, out);
}

// Round 11
// 323.423 us; speedup vs baseline: 1.3244x; 1.3244x over previous
//
#include <hip/hip_runtime.h>
#include <cstdint>

#define BB 2048
#define TT 200
#define DD 128
#define H1 128
#define H2 64
#define MR (BB * TT)           // 409600 flat rows
#define MASK_PAD -4294967295.0f

typedef __attribute__((ext_vector_type(8))) short short8;
typedef __attribute__((ext_vector_type(4))) float floatx4;

// ws layout (float offsets)
#define WS_WQAC   0          // fp32 [128][128]  Wqac[d][h] = W0a+W0c
#define WS_WCATT  16384      // bf16 [128][256]  WcatT[h][k] (16384 float slots)
#define WS_W1TB   32768      // bf16 [64][128]   W1^T        (4096 float slots)
#define WS_QAS    36864      // fp32 [2048][128] qA
#define WS_LOGITS 299008     // fp32 [409600]    raw logits

static __device__ __forceinline__ unsigned short f2bf(float x) {
  union { float f; unsigned int u; } v; v.f = x;
  unsigned int r = v.u + 0x7FFF + ((v.u >> 16) & 1);  // RNE
  return (unsigned short)(r >> 16);
}

// ---------------------------------------------------------------------------
// Fold: Wqac (fp32), WcatT = [(W0b-W0c); W0d]^T (bf16 [128 h][256 k]),
//       W1tb = W1^T (bf16 [64 g][128 h]).
// ---------------------------------------------------------------------------
__global__ __launch_bounds__(256) void din_fold(
    const float* __restrict__ W0, const float* __restrict__ W1,
    float* __restrict__ ws) {
  int i = blockIdx.x * blockDim.x + threadIdx.x;
  if (i < 16384) {
    int d = i >> 7, h = i & 127;
    ws[WS_WQAC + i] = W0[d * 128 + h] + W0[(256 + d) * 128 + h];
  } else if (i < 49152) {
    int j = i - 16384;           // [h][k]
    int h = j >> 8, k = j & 255;
    float v;
    if (k < 128) v = W0[(128 + k) * 128 + h] - W0[(256 + k) * 128 + h];
    else         v = W0[(384 + (k - 128)) * 128 + h];
    ((unsigned short*)(ws + WS_WCATT))[j] = f2bf(v);
  } else if (i < 57344) {
    int j = i - 49152;           // [g][h]
    int g = j >> 7, h = j & 127;
    ((unsigned short*)(ws + WS_W1TB))[j] = f2bf(W1[h * 64 + g]);
  }
}

// ---------------------------------------------------------------------------
// QA: qas_g[b][h] = b0[h] + sum_d q[b][d] * Wqac[d][h]
// ---------------------------------------------------------------------------
__global__ __launch_bounds__(128) void din_qa(
    const float* __restrict__ query, const float* __restrict__ b0,
    const float* __restrict__ ws, float* __restrict__ qas_g) {
  const int b = blockIdx.x;
  const int h = threadIdx.x;
  __shared__ float qsh[DD];
  qsh[h] = query[(size_t)b * DD + h];
  __syncthreads();
  float acc = b0[h];
  const float* wq = ws + WS_WQAC + h;
  #pragma unroll 8
  for (int d = 0; d < DD; ++d) acc += qsh[d] * wq[d * 128];
  qas_g[(size_t)b * H1 + h] = acc;
}

// ---------------------------------------------------------------------------
// Logits as ONE flat GEMM over 409600 rows. 6400 blocks x 64 rows.
// Wave w owns rows [blk*64 + 16w, +16): builds X = [k | q*k] in regs,
// GEMM1 vs shared WcatT (L2-hot), +qA +PReLU(a0), wave-private LDS
// transpose, GEMM2 vs W1T (L2-hot), +b1 +PReLU(a1), dot Wout -> logit.
// ZERO barriers; waves and blocks fully independent.
// ---------------------------------------------------------------------------
__global__ __launch_bounds__(256, 2) void din_logits(
    const float* __restrict__ key, const float* __restrict__ query,
    const float* __restrict__ ws, const float* __restrict__ qas_g,
    const float* __restrict__ a0, const float* __restrict__ a1,
    const float* __restrict__ b1, const float* __restrict__ Wout,
    const float* __restrict__ bout, float* __restrict__ lgout) {
  const int tid = threadIdx.x;
  const int w = tid >> 6;
  const int l = tid & 63;
  const int lr = l & 15;
  const int kgrp = l >> 4;

  __shared__ unsigned short A2[4][16 * 128];   // 16 KB, wave-private quarters

  const unsigned short* wc = (const unsigned short*)(ws + WS_WCATT);
  const unsigned short* w1 = (const unsigned short*)(ws + WS_W1TB);

  const int grbase = blockIdx.x * 64 + w * 16;     // this wave's 16 rows
  char* a2b = (char*)A2[w];

  // ---- input row (A-operand row = lane lr) ----
  const int gr_in = grbase + lr;                   // < 409600
  const int b_in = gr_in / 200;
  const float* krow = key + (size_t)gr_in * DD;
  const float* qrow = query + (size_t)b_in * DD;

  // ---- build af[8]: ks 0-3 = bf16(k), ks 4-7 = bf16(q*k) ----
  short8 af[8];
  #pragma unroll
  for (int ks = 0; ks < 4; ++ks) {
    int d0 = ks * 32 + kgrp * 8;
    float4 k0 = *(const float4*)(krow + d0);
    float4 k1 = *(const float4*)(krow + d0 + 4);
    float4 q0 = *(const float4*)(qrow + d0);
    float4 q1 = *(const float4*)(qrow + d0 + 4);
    short8 ak, aq;
    ak[0] = (short)f2bf(k0.x); ak[1] = (short)f2bf(k0.y);
    ak[2] = (short)f2bf(k0.z); ak[3] = (short)f2bf(k0.w);
    ak[4] = (short)f2bf(k1.x); ak[5] = (short)f2bf(k1.y);
    ak[6] = (short)f2bf(k1.z); ak[7] = (short)f2bf(k1.w);
    aq[0] = (short)f2bf(q0.x * k0.x); aq[1] = (short)f2bf(q0.y * k0.y);
    aq[2] = (short)f2bf(q0.z * k0.z); aq[3] = (short)f2bf(q0.w * k0.w);
    aq[4] = (short)f2bf(q1.x * k1.x); aq[5] = (short)f2bf(q1.y * k1.y);
    aq[6] = (short)f2bf(q1.z * k1.z); aq[7] = (short)f2bf(q1.w * k1.w);
    af[ks] = ak; af[ks + 4] = aq;
  }

  // ---- output rows (C rows = kgrp*4 + r) : b,t per r ----
  int bo[4], to[4];
  #pragma unroll
  for (int r = 0; r < 4; ++r) {
    int gro = grbase + kgrp * 4 + r;
    bo[r] = gro / 200;
    to[r] = gro - bo[r] * 200;
  }

  // ---- GEMM1: 8 k-steps x 8 n-tiles, B streamed from L2 ----
  floatx4 acc1[8];
  #pragma unroll
  for (int nt = 0; nt < 8; ++nt) acc1[nt] = (floatx4)(0.0f);
  #pragma unroll
  for (int ks = 0; ks < 8; ++ks) {
    #pragma unroll
    for (int nt = 0; nt < 8; ++nt) {
      short8 bf = *(const short8*)(wc + (nt * 16 + lr) * 256 + ks * 32 + kgrp * 8);
      acc1[nt] = __builtin_amdgcn_mfma_f32_16x16x32_bf16(af[ks], bf, acc1[nt], 0, 0, 0);
    }
  }

  // ---- epilogue 1: +qA[bo], PReLU(a0[to]), write to wave-private LDS ----
  #pragma unroll
  for (int nt = 0; nt < 8; ++nt) {
    int h = nt * 16 + lr;
    #pragma unroll
    for (int r = 0; r < 4; ++r) {
      int t_loc = kgrp * 4 + r;
      float v = acc1[nt][r] + qas_g[(size_t)bo[r] * H1 + h];
      float a = a0[to[r] * H1 + h];
      v = v > 0.0f ? v : a * v;
      *(unsigned short*)(a2b + t_loc * 256 + ((h * 2) ^ ((t_loc & 7) << 4))) = f2bf(v);
    }
  }

  // ---- GEMM2: A from private LDS, B = W1T streamed from L2 ----
  short8 a2f[4];
  #pragma unroll
  for (int ks = 0; ks < 4; ++ks) {
    a2f[ks] = *(const short8*)(a2b + lr * 256 +
                               ((ks * 64 + kgrp * 16) ^ ((lr & 7) << 4)));
  }
  floatx4 acc2[4];
  #pragma unroll
  for (int nt = 0; nt < 4; ++nt) acc2[nt] = (floatx4)(0.0f);
  #pragma unroll
  for (int ks = 0; ks < 4; ++ks) {
    #pragma unroll
    for (int nt = 0; nt < 4; ++nt) {
      short8 bf = *(const short8*)(w1 + (nt * 16 + lr) * 128 + ks * 32 + kgrp * 8);
      acc2[nt] = __builtin_amdgcn_mfma_f32_16x16x32_bf16(a2f[ks], bf, acc2[nt], 0, 0, 0);
    }
  }

  // ---- epilogue 2: +b1, PReLU(a1[to]), *Wout, 16-lane reduce -> logits ----
  float p[4] = {0.f, 0.f, 0.f, 0.f};
  #pragma unroll
  for (int nt = 0; nt < 4; ++nt) {
    int g = nt * 16 + lr;
    float b1v = b1[g];
    float wov = Wout[g];
    #pragma unroll
    for (int r = 0; r < 4; ++r) {
      float x = acc2[nt][r] + b1v;
      float a = a1[to[r] * H2 + g];
      x = x > 0.0f ? x : a * x;
      p[r] += x * wov;
    }
  }
  #pragma unroll
  for (int m = 1; m < 16; m <<= 1) {
    #pragma unroll
    for (int r = 0; r < 4; ++r) p[r] += __shfl_xor(p[r], m);
  }
  if (lr == 0) {
    float bout0 = bout[0];
    #pragma unroll
    for (int r = 0; r < 4; ++r) {
      lgout[grbase + kgrp * 4 + r] = bout0 + p[r];
    }
  }
}

// ---------------------------------------------------------------------------
// PV (+mask+softmax): out[b][d] = softmax(masked logits[b]) . val[b]
// ---------------------------------------------------------------------------
__global__ __launch_bounds__(256) void din_pv(
    const float* __restrict__ val, const int* __restrict__ mask,
    const float* __restrict__ logits, float* __restrict__ out) {
  const int b = blockIdx.x;
  const int tid = threadIdx.x;
  const int w = tid >> 6;
  const int l = tid & 63;
  __shared__ float eL[TT];
  __shared__ float red4[8];
  __shared__ float red[8 * DD];

  float lv = -INFINITY;
  if (tid < TT) {
    float lg = logits[(size_t)b * TT + tid];
    int mk = mask[(size_t)b * TT + tid];
    lv = (mk == 0) ? MASK_PAD : lg;
  }
  {
    float m = lv;
    #pragma unroll
    for (int off = 32; off >= 1; off >>= 1) m = fmaxf(m, __shfl_xor(m, off));
    if (l == 0) red4[w] = m;
  }
  __syncthreads();
  float mx = fmaxf(fmaxf(red4[0], red4[1]), fmaxf(red4[2], red4[3]));
  float e = (tid < TT) ? __expf(lv - mx) : 0.0f;
  {
    float s = e;
    #pragma unroll
    for (int off = 32; off >= 1; off >>= 1) s += __shfl_xor(s, off);
    if (l == 0) red4[4 + w] = s;
  }
  __syncthreads();
  float inv = 1.0f / (red4[4] + red4[5] + red4[6] + red4[7]);
  if (tid < TT) eL[tid] = e * inv;
  __syncthreads();

  const int group = tid >> 5;
  const int d4 = (tid & 31) * 4;
  const float* vb = val + (size_t)b * TT * DD;
  float4 acc4 = make_float4(0.f, 0.f, 0.f, 0.f);
  #pragma unroll 5
  for (int t = group * 25; t < group * 25 + 25; ++t) {
    float4 v = *(const float4*)(vb + (size_t)t * DD + d4);
    float wt = eL[t];
    acc4.x += wt * v.x; acc4.y += wt * v.y;
    acc4.z += wt * v.z; acc4.w += wt * v.w;
  }
  *(float4*)&red[group * DD + d4] = acc4;
  __syncthreads();
  if (tid < DD) {
    float s = 0.0f;
    #pragma unroll
    for (int g = 0; g < 8; ++g) s += red[g * DD + tid];
    out[(size_t)b * DD + tid] = s;
  }
}

extern "C" void kernel_launch(void* const* d_in, const int* in_sizes, int n_in,
                              void* d_out, int out_size, void* d_ws, size_t ws_size,
                              hipStream_t stream) {
  const float* query = (const float*)d_in[0];
  const float* key   = (const float*)d_in[1];
  const float* val   = (const float*)d_in[2];
  const int*   mask  = (const int*)d_in[3];
  const float* W0    = (const float*)d_in[4];
  const float* b0    = (const float*)d_in[5];
  const float* a0    = (const float*)d_in[6];
  const float* W1    = (const float*)d_in[7];
  const float* b1    = (const float*)d_in[8];
  const float* a1    = (const float*)d_in[9];
  const float* Wout  = (const float*)d_in[10];
  const float* bout  = (const float*)d_in[11];
  float* out = (float*)d_out;
  float* ws  = (float*)d_ws;
  float* qas_g  = ws + WS_QAS;
  float* logits = ws + WS_LOGITS;

  hipLaunchKernelGGL(din_fold, dim3(224), dim3(256), 0, stream, W0, W1, ws);
  hipLaunchKernelGGL(din_qa, dim3(BB), dim3(128), 0, stream, query, b0, ws, qas_g);
  hipLaunchKernelGGL(din_logits, dim3(MR / 64), dim3(256), 0, stream,
                     key, query, ws, qas_g, a0, a1, b1, Wout, bout, logits);
  hipLaunchKernelGGL(din_pv, dim3(BB), dim3(256), 0, stream, val, mask, logits, out);
}